// Round 4
// baseline (174.362 us; speedup 1.0000x reference)
//
#include <hip/hip_runtime.h>

// DeepPatchEncoder collapses to:
//   out[b, n0, d] = X[b, y, x, c] + bias[n0, d]
// where bias[n0,d] = pos_emb[n0,d] + BN(conv2x2s2(pos_emb-as-image))[n1, y%8, x%8, c]
// bias is batch-independent -> precompute into d_ws (602 KB), then a
// memory-bound permuted add over 128*196*768 floats (154 MB -> ~24.5 us floor).
//
// R4: same as R3 but nontemporal builtins use native ext_vector_type
// (clang rejects HIP_vector_type<float,4>* for __builtin_nontemporal_*).

#define TOT_OUT (128 * 196 * 768)           // 19,267,584
#define TOT_OUT4 (TOT_OUT / 4)              // 4,816,896

typedef float vfloat4 __attribute__((ext_vector_type(4)));

__global__ void __launch_bounds__(256) compute_bias_v3(
    const float* __restrict__ pos_emb,   // [196, 768]
    const float* __restrict__ conv_w,    // [2,2,196,784] HWIO -> viewed [784, 784]
    const float* __restrict__ bn_gamma,  // [784]
    const float* __restrict__ bn_beta,
    const float* __restrict__ bn_mean,
    const float* __restrict__ bn_var,
    float* __restrict__ bias)            // [196, 768] (d_ws)
{
    __shared__ float At[784 * 8];        // A transposed: At[k][j], j = 0..7
    __shared__ float4 red[2][4][64];     // tap-reduction buffer (2 float4 per lane)

    const int mg = blockIdx.x;           // 0..23: (c, i)
    const int ot = blockIdx.y;           // 0..12: o-tile of 64
    const int c  = mg >> 3;
    const int i  = mg & 7;
    const int t  = threadIdx.x;

    // Stage A into LDS, transposed. At[k*8+j] = pos_emb[n, ((2i+di)*16 + 2j+dj)*3 + c]
    // with k = (di*2+dj)*196 + n.
    for (int idx = t; idx < 784 * 8; idx += 256) {
        const int j   = idx & 7;
        const int k   = idx >> 3;
        const int tap = k / 196;
        const int n   = k - tap * 196;
        const int di = tap >> 1, dj = tap & 1;
        const int y16 = 2 * i + di;
        const int x16 = 2 * j + dj;
        At[idx] = pos_emb[n * 768 + (y16 * 16 + x16) * 3 + c];
    }
    __syncthreads();

    const int o_lane = t & 63;
    const int tap    = t >> 6;
    const int o      = ot * 64 + o_lane;
    const int o_c    = o < 784 ? o : 783;   // clamp: keeps w loads in-bounds
    const float* __restrict__ wp = conv_w + (size_t)(tap * 196) * 784 + o_c;
    const float4* __restrict__ At4 = reinterpret_cast<const float4*>(At) + tap * 196 * 2;

    float4 accL = {0.f, 0.f, 0.f, 0.f};
    float4 accH = {0.f, 0.f, 0.f, 0.f};
#pragma unroll 4
    for (int n = 0; n < 196; ++n) {
        const float  wv = wp[n * 784];
        const float4 aL = At4[n * 2];
        const float4 aH = At4[n * 2 + 1];
        accL.x += aL.x * wv;  accL.y += aL.y * wv;
        accL.z += aL.z * wv;  accL.w += aL.w * wv;
        accH.x += aH.x * wv;  accH.y += aH.y * wv;
        accH.z += aH.z * wv;  accH.w += aH.w * wv;
    }
    red[0][tap][o_lane] = accL;
    red[1][tap][o_lane] = accH;
    __syncthreads();

    if (t < 64) {
        const int oo = ot * 64 + t;
        if (oo < 784) {
            float sum[8];
#pragma unroll
            for (int h = 0; h < 2; ++h) {
                const float4 r0 = red[h][0][t], r1 = red[h][1][t];
                const float4 r2 = red[h][2][t], r3 = red[h][3][t];
                sum[h * 4 + 0] = r0.x + r1.x + r2.x + r3.x;
                sum[h * 4 + 1] = r0.y + r1.y + r2.y + r3.y;
                sum[h * 4 + 2] = r0.z + r1.z + r2.z + r3.z;
                sum[h * 4 + 3] = r0.w + r1.w + r2.w + r3.w;
            }
            const float scale = bn_gamma[oo] * rsqrtf(bn_var[oo] + 1e-3f);
            const float mb = bn_mean[oo], bb = bn_beta[oo];
            const int y8 = oo / 28, x8 = oo % 28;
            const int y = y8 * 8 + i;
            const int n0_row = (y >> 4) * 14;
            const int d_row  = (y & 15) * 16;
#pragma unroll
            for (int j = 0; j < 8; ++j) {
                const float val = (sum[j] - mb) * scale + bb;
                const int x = x8 * 8 + j;
                const int n0 = n0_row + (x >> 4);
                const int d  = (d_row + (x & 15)) * 3 + c;
                bias[n0 * 768 + d] = pos_emb[n0 * 768 + d] + val;
            }
        }
    }
}

__global__ void __launch_bounds__(256) add_bias_kernel(
    const float* __restrict__ X,      // [128, 224, 224, 3]
    const float* __restrict__ bias,   // [196, 768]
    float* __restrict__ out)          // [128, 196, 768]
{
    int tid = blockIdx.x * blockDim.x + threadIdx.x;
    if (tid >= TOT_OUT4) return;
    const int flat = tid * 4;
    const int b = flat / 150528;           // 196*768
    const int rem = flat - b * 150528;
    const int n0 = rem / 768;
    const int d = rem - n0 * 768;
    const int py = d / 48;                 // 16*3
    const int r = d - py * 48;
    const int y = (n0 / 14) * 16 + py;
    const int xcol = (n0 % 14) * 48 + r;   // (x*3 + c) within the row
    // all offsets are multiples of 4 floats -> float4 safe
    // X is streamed once, out written once: nontemporal on both
    const vfloat4 xv = __builtin_nontemporal_load(
        reinterpret_cast<const vfloat4*>(X + (size_t)b * 150528 + y * 672 + xcol));
    const float4 bv = *reinterpret_cast<const float4*>(bias + rem);
    vfloat4 ov;
    ov.x = xv.x + bv.x;
    ov.y = xv.y + bv.y;
    ov.z = xv.z + bv.z;
    ov.w = xv.w + bv.w;
    __builtin_nontemporal_store(ov, reinterpret_cast<vfloat4*>(out + flat));
}

extern "C" void kernel_launch(void* const* d_in, const int* in_sizes, int n_in,
                              void* d_out, int out_size, void* d_ws, size_t ws_size,
                              hipStream_t stream) {
    const float* X        = (const float*)d_in[0];
    const float* pos_emb  = (const float*)d_in[1];
    const float* conv_w   = (const float*)d_in[2];
    const float* bn_gamma = (const float*)d_in[3];
    const float* bn_beta  = (const float*)d_in[4];
    const float* bn_mean  = (const float*)d_in[5];
    const float* bn_var   = (const float*)d_in[6];
    float* out  = (float*)d_out;
    float* bias = (float*)d_ws;   // 196*768 floats = 602,112 bytes

    dim3 bias_grid(24, 13);       // 24 (c,i) m-groups x 13 o-tiles of 64
    compute_bias_v3<<<bias_grid, 256, 0, stream>>>(
        pos_emb, conv_w, bn_gamma, bn_beta, bn_mean, bn_var, bias);
    add_bias_kernel<<<(TOT_OUT4 + 255) / 256, 256, 0, stream>>>(X, bias, out);
}